// Round 2
// baseline (1028.955 us; speedup 1.0000x reference)
//
#include <hip/hip_runtime.h>
#include <hip/hip_fp16.h>
#include <math.h>

// Problem constants
#define V    20000
#define SCV  4000
#define LL   15
#define OUTN (16384 * 128)   // B*S*D

#define LEAF_BIT 0x40000000
#define REF_MASK 0x3FFFFFFF
#define ROOT_BIT 0x20000000   // on E.x only: node is a tree root (write hInt only)
#define SLOT_MASK 0x1FFFFFFF
#define DUMMY_SLOT 89999     // total internal nodes ~80k < 89999

// ---- workspace layout (bytes) ---- (LT/RT/leafH slots now unused)
#define OFF_COUNTS 0
#define OFF_ROOT   128
#define OFF_LISTS  80384
#define OFF_LEAFC  5968384
#define OFF_LEAFHH 8016384
#define OFF_WT     19280384
#define OFF_BIAS   19608064
#define OFF_HINT   19610624
#define OFF_CINT   65690624
#define OFF_HH     111770624
#define OFF_USED   134810624

// per-height lists: h1@0 (cap 80000), h2@80000, h3@120000, h4@160000,
// h5@180000, h6@200000, h7@220000
__device__ __constant__ int d_listOff[8] = {0, 0, 80000, 120000, 160000, 180000, 200000, 220000};

#define FBLK 256     // == #CUs: guaranteed co-resident at 1 block/CU
#define FT   512     // 8 waves
#define MT   128

typedef _Float16 f16x8 __attribute__((ext_vector_type(8)));
typedef float    f32x4 __attribute__((ext_vector_type(4)));

__device__ __forceinline__ float sigm(float x) { return 1.0f / (1.0f + expf(-x)); }

// LDS union across phases (phases separated by barriers)
union SharedU {
    struct { __half Ah[64][264]; int4 meta[64]; } f;   // MFMA phases (~34.8 KB)
    struct { float T[64][65]; } w;                     // WT transpose (~16.6 KB)
    struct {                                           // meta phase (~35.9 KB)
        int  sHei[MT][17];
        int  sRef[MT][17];
        int4 ebuf[MT][7];
        int  ebin[MT][7];
        int  locCnt[8];
        int  basePos[8];
        int  scanBuf[MT];
        int  blockBase;
    } m;
};

// device-scope grid barrier: release (flush) -> arrive -> spin -> acquire (inv)
__device__ __forceinline__ void grid_barrier(int* bar) {
    __syncthreads();
    if (threadIdx.x == 0) {
        __threadfence();
        __hip_atomic_fetch_add(bar, 1, __ATOMIC_RELEASE, __HIP_MEMORY_SCOPE_AGENT);
        while (__hip_atomic_load(bar, __ATOMIC_ACQUIRE, __HIP_MEMORY_SCOPE_AGENT) < (int)gridDim.x)
            __builtin_amdgcn_s_sleep(2);
        __threadfence();
    }
    __syncthreads();
}

__launch_bounds__(FT, 2)
__global__ void forest_kernel(const int* __restrict__ input,
                              const int* __restrict__ node_ids,
                              const int* __restrict__ left,
                              const int* __restrict__ right,
                              const int* __restrict__ last,
                              const float* __restrict__ emb,
                              const float* __restrict__ Wl, const float* __restrict__ Wlb,
                              const float* __restrict__ Wr, const float* __restrict__ Wrb,
                              int* counts, int* rootSlot, int4* lists,
                              float* leafC, __half* leafHh,
                              __half* WT, float* biasSum,
                              float* hInt, float* cInt, __half* hH,
                              unsigned char* used, float4* out) {
    __shared__ SharedU S;
    int t = threadIdx.x;
    int* bar = counts + 16;   // counts[16..24]: 9 barrier slots, pre-zeroed

    // ================= P0: leaf states, WT transpose, biasSum, mark =================
    // leaf (h,c) per sub-char id; only fp16 h + f32 c are consumed downstream
    for (int r = blockIdx.x * 4 + (t >> 7); r < SCV; r += gridDim.x * 4) {
        int i = t & 127;
        const float* e = emb + r * 640;
        float c = sigm(e[i]) * tanhf(e[512 + i]);
        float h = sigm(e[384 + i]) * tanhf(c);
        leafC[r * 128 + i] = c;
        leafHh[r * 128 + i] = __float2half(h);
    }
    // mark used tokens
    for (int i = blockIdx.x * FT + t; i < 16384; i += gridDim.x * FT)
        used[input[i]] = 1;
    // bias sum
    if (blockIdx.x == 40)
        for (int i = t; i < 640; i += FT) biasSum[i] = Wlb[i] + Wrb[i];
    // WT[n][k] = fp16([Wl;Wr][k][n]); 40 tiles of 64x64
    for (int tile = blockIdx.x; tile < 40; tile += gridDim.x) {
        int kb = (tile & 3) * 64, nb = (tile >> 2) * 64;
        int tx = t & 63, ty = (t >> 6) & 3;
        if (t < 256) {
            for (int kk = ty; kk < 64; kk += 4) {
                int k = kb + kk;
                const float* Wsrc = (k < 128) ? (Wl + k * 640) : (Wr + (k - 128) * 640);
                S.w.T[kk][tx] = Wsrc[nb + tx];
            }
        }
        __syncthreads();
        if (t < 256) {
            for (int nn = ty; nn < 64; nn += 4)
                WT[(nb + nn) * 256 + kb + tx] = __float2half(S.w.T[tx][nn]);
        }
        __syncthreads();
    }
    grid_barrier(&bar[0]);

    // ================= P1: metadata (heights, compact slots, per-height lists) ======
    {
        int tile = blockIdx.x;                 // tiles 0..156 active
        bool act = (tile * MT) < V;
        if (t < 8) S.m.locCnt[t] = 0;
        __syncthreads();
        int v = tile * MT + t;
        int nInt = 0;
        if (act && t < MT && v < V && used[v]) {
            int l15[LL], r15[LL], id15[LL];
#pragma unroll
            for (int j = 0; j < LL; ++j) {
                l15[j]  = left[v * LL + j];
                r15[j]  = right[v * LL + j];
                id15[j] = node_ids[v * LL + j];
            }
            int lastv = last[v];
#pragma unroll
            for (int j = 0; j < LL; ++j) {
                if (j <= lastv) {
                    int l = l15[j];
                    if (l < 0) {
                        S.m.sHei[t][j] = 0;
                        S.m.sRef[t][j] = LEAF_BIT | id15[j];
                    } else {
                        int r = r15[j];
                        int hl = S.m.sHei[t][l], hr = S.m.sHei[t][r];
                        int hh = 1 + (hl > hr ? hl : hr);
                        S.m.sHei[t][j] = hh;
                        int pos = atomicAdd(&S.m.locCnt[hh], 1);
                        int flag = (j == lastv) ? ROOT_BIT : 0;
                        S.m.ebuf[t][nInt] = make_int4(nInt | flag, id15[j],
                                                      S.m.sRef[t][l], S.m.sRef[t][r]);
                        S.m.ebin[t][nInt] = (hh << 16) | pos;
                        S.m.sRef[t][j] = nInt;
                        ++nInt;
                    }
                }
            }
        }
        if (t < MT) S.m.scanBuf[t] = nInt;
        __syncthreads();
        for (int d = 1; d < MT; d <<= 1) {
            int val = (t >= d && t < MT) ? S.m.scanBuf[t - d] : 0;
            __syncthreads();
            if (t < MT) S.m.scanBuf[t] += val;
            __syncthreads();
        }
        if (act && t == 0) S.m.blockBase = atomicAdd(&counts[31], S.m.scanBuf[MT - 1]);
        if (act && t < 8) {
            int c = S.m.locCnt[t];
            S.m.basePos[t] = c ? atomicAdd(&counts[t], c) : 0;
        }
        __syncthreads();
        if (act && t < MT) {
            int treeBase = S.m.blockBase + S.m.scanBuf[t] - nInt;
            if (nInt > 0 && v < V) rootSlot[v] = treeBase + nInt - 1;
            for (int e = 0; e < nInt; ++e) {
                int4 E  = S.m.ebuf[t][e];
                int md  = S.m.ebin[t][e];
                int hh  = md >> 16, pos = md & 0xFFFF;
                E.x += treeBase;                                   // ROOT_BIT preserved
                E.z = (E.z & LEAF_BIT) ? E.z : (E.z + treeBase);
                E.w = (E.w & LEAF_BIT) ? E.w : (E.w + treeBase);
                lists[d_listOff[hh] + S.m.basePos[hh] + pos] = E;
            }
        }
    }
    grid_barrier(&bar[1]);

    // ================= P2..P8: MFMA rounds, heights 1..7, unified K=256 =============
    // block = 8 waves; 64 nodes/group; wave w owns cols {128p + 16w + ln15, p=0..4}
    // = the 5 gates of dim 16w+ln15 -> full in-register LSTM epilogue.
    int lane = t & 63, wave = t >> 6;
    int ln15 = lane & 15, quad = lane >> 4;
    for (int h = 1; h <= 7; ++h) {
        int cnt = counts[h];
        const int4* list = lists + d_listOff[h];
        int nGroups = (cnt + 63) >> 6;
        for (int grp = blockIdx.x; grp < nGroups; grp += gridDim.x) {
            int base = grp * 64;
            int rows = cnt - base; if (rows > 64) rows = 64;
            if (t < 64) {
                int4 E;
                if (t < rows) E = list[base + t];
                else { E.x = DUMMY_SLOT; E.y = 0; E.z = LEAF_BIT; E.w = LEAF_BIT; }
                S.f.meta[t] = E;
            }
            __syncthreads();
            // stage A rows: [hl fp16 (k 0..127) | hr fp16 (k 128..255)]
#pragma unroll
            for (int it = 0; it < 4; ++it) {
                int idx = t + it * FT;
                int m = idx >> 5, q = idx & 31;
                int ref = (q < 16) ? S.f.meta[m].z : S.f.meta[m].w;
                const __half* hs = (ref & LEAF_BIT) ? leafHh : hH;
                uint4 vv = *(const uint4*)(hs + (ref & REF_MASK) * 128 + (q & 15) * 8);
                *(uint4*)(&S.f.Ah[m][q * 8]) = vv;
            }
            // C init: emb + (Wlb+Wrb)
            float bs[5];
#pragma unroll
            for (int p = 0; p < 5; ++p) bs[p] = biasSum[p * 128 + 16 * wave + ln15];
            f32x4 acc[4][5];
#pragma unroll
            for (int c = 0; c < 4; ++c)
#pragma unroll
                for (int r = 0; r < 4; ++r) {
                    const float* eb = emb + S.f.meta[c * 16 + quad * 4 + r].y * 640
                                          + 16 * wave + ln15;
#pragma unroll
                    for (int p = 0; p < 5; ++p)
                        acc[c][p][r] = eb[p * 128] + bs[p];
                }
            __syncthreads();
            // K loop: 8 steps of 32; 5 B-frags + 4 A-frags -> 20 independent MFMAs
            const __half* wbase = WT + (16 * wave + ln15) * 256 + quad * 8;
#pragma unroll 2
            for (int kb = 0; kb < 8; ++kb) {
                f16x8 bf[5];
#pragma unroll
                for (int p = 0; p < 5; ++p)
                    bf[p] = *(const f16x8*)((const void*)(wbase + p * 32768 + kb * 32));
                f16x8 af[4];
#pragma unroll
                for (int c = 0; c < 4; ++c)
                    af[c] = *(const f16x8*)((const void*)&S.f.Ah[c * 16 + ln15][kb * 32 + quad * 8]);
#pragma unroll
                for (int p = 0; p < 5; ++p)
#pragma unroll
                    for (int c = 0; c < 4; ++c)
                        acc[c][p] = __builtin_amdgcn_mfma_f32_16x16x32_f16(af[c], bf[p], acc[c][p], 0, 0, 0);
            }
            // in-register LSTM epilogue: dim d = 16*wave + ln15, gates = p
            int d = 16 * wave + ln15;
#pragma unroll
            for (int c = 0; c < 4; ++c)
#pragma unroll
                for (int r = 0; r < 4; ++r) {
                    int4 E = S.f.meta[c * 16 + quad * 4 + r];
                    float ig = acc[c][0][r], lfg = acc[c][1][r], rfg = acc[c][2][r];
                    float og = acc[c][3][r], ug = acc[c][4][r];
                    float cl = ((E.z & LEAF_BIT) ? leafC : cInt)[(E.z & REF_MASK) * 128 + d];
                    float cr = ((E.w & LEAF_BIT) ? leafC : cInt)[(E.w & REF_MASK) * 128 + d];
                    float cc = sigm(ig) * tanhf(ug) + sigm(lfg) * cl + sigm(rfg) * cr;
                    float hh2 = sigm(og) * tanhf(cc);
                    int slot = E.x & SLOT_MASK;
                    if (E.x & ROOT_BIT) {
                        hInt[slot * 128 + d] = hh2;      // root: only f32 h is read (gather)
                    } else {
                        cInt[slot * 128 + d] = cc;       // non-root: c + fp16 h are read
                        hH[slot * 128 + d] = __float2half(hh2);
                    }
                }
            __syncthreads();   // protect meta/Ah before next group
        }
        grid_barrier(&bar[2 + (h - 1)]);
    }

    // ================= P9: gather out[b,s,:] = h_root[input[b,s]] ===================
    for (int idx = blockIdx.x * FT + t; idx < OUTN / 4; idx += gridDim.x * FT) {
        int token = input[idx >> 5];
        int d = idx & 31;
        out[idx] = ((const float4*)hInt)[rootSlot[token] * 32 + d];
    }
}

extern "C" void kernel_launch(void* const* d_in, const int* in_sizes, int n_in,
                              void* d_out, int out_size, void* d_ws, size_t ws_size,
                              hipStream_t stream) {
    const int*   input    = (const int*)d_in[0];
    const int*   node_ids = (const int*)d_in[1];
    const int*   left     = (const int*)d_in[2];
    const int*   right    = (const int*)d_in[3];
    const int*   last     = (const int*)d_in[4];
    const float* emb      = (const float*)d_in[5];
    const float* Wl       = (const float*)d_in[6];
    const float* Wlb      = (const float*)d_in[7];
    const float* Wr       = (const float*)d_in[8];
    const float* Wrb      = (const float*)d_in[9];
    float* out = (float*)d_out;

    char* ws = (char*)d_ws;
    int*    counts   = (int*)(ws + OFF_COUNTS);
    int*    rootSlot = (int*)(ws + OFF_ROOT);
    int4*   lists    = (int4*)(ws + OFF_LISTS);
    float*  leafC    = (float*)(ws + OFF_LEAFC);
    __half* leafHh   = (__half*)(ws + OFF_LEAFHH);
    __half* WT       = (__half*)(ws + OFF_WT);
    float*  biasSum  = (float*)(ws + OFF_BIAS);
    float*  hInt     = (float*)(ws + OFF_HINT);
    float*  cInt     = (float*)(ws + OFF_CINT);
    __half* hH       = (__half*)(ws + OFF_HH);
    unsigned char* usedp = (unsigned char*)(ws + OFF_USED);

    (void)hipMemsetAsync(counts, 0, 128, stream);   // counts + barrier slots
    (void)hipMemsetAsync(usedp, 0, V, stream);

    forest_kernel<<<FBLK, FT, 0, stream>>>(input, node_ids, left, right, last,
                                           emb, Wl, Wlb, Wr, Wrb,
                                           counts, rootSlot, lists, leafC, leafHh,
                                           WT, biasSum, hInt, cInt, hH,
                                           usedp, (float4*)out);
}

// Round 3
// 453.626 us; speedup vs baseline: 2.2683x; 2.2683x over previous
//
#include <hip/hip_runtime.h>
#include <hip/hip_fp16.h>
#include <math.h>

// Problem constants
#define V    20000
#define SCV  4000
#define LL   15
#define OUTN (16384 * 128)   // B*S*D

#define LEAF_BIT 0x40000000
#define REF_MASK 0x3FFFFFFF
#define ROOT_BIT 0x20000000   // on E.x only: node is a tree root (write hInt only)
#define SLOT_MASK 0x1FFFFFFF
#define DUMMY_SLOT 89999     // total internal nodes ~80k < 89999

// ---- workspace layout (bytes) ----
#define OFF_COUNTS 0
#define OFF_ROOT   128
#define OFF_LISTS  80384
#define OFF_LEAFC  5968384
#define OFF_LEAFHH 8016384
#define OFF_WT     19280384
#define OFF_BIAS   19608064
#define OFF_HINT   19610624
#define OFF_CINT   65690624
#define OFF_HH     111770624
#define OFF_USED   134810624

// per-height lists: h1@0 (cap 80000), h2@80000, h3@120000, h4@160000,
// h5@180000, h6@200000, h7@220000
__device__ __constant__ int d_listOff[8] = {0, 0, 80000, 120000, 160000, 180000, 200000, 220000};

#define FBLK  256    // == #CUs: guaranteed co-resident at 1 block/CU
#define FT    512    // 8 waves
#define MT    128
#define NTAIL 16     // blocks participating in heights 5-7 (few groups)

typedef _Float16 f16x8 __attribute__((ext_vector_type(8)));
typedef float    f32x4 __attribute__((ext_vector_type(4)));

__device__ __forceinline__ float sigm(float x) { return 1.0f / (1.0f + expf(-x)); }

// LDS union across phases (phases separated by barriers)
union SharedU {
    struct { __half Ah[64][264]; int4 meta[64]; } f;   // MFMA phases (~34.8 KB)
    struct { float T[64][65]; } w;                     // WT transpose (~16.6 KB)
    struct {                                           // meta phase (~35.9 KB)
        int  sHei[MT][17];
        int  sRef[MT][17];
        int4 ebuf[MT][7];
        int  ebin[MT][7];
        int  locCnt[8];
        int  basePos[8];
        int  scanBuf[MT];
        int  blockBase;
    } m;
};

// Counting grid barrier. CRITICAL: poll with RELAXED (plain agent-coherent
// load, no buffer_inv); pay release(wb)/acquire(inv) fences ONCE via
// __threadfence() around the spin. The previous ACQUIRE-per-poll emitted a
// full L1+L2 invalidate every iteration -> 84MB refetch storm, 985us.
__device__ __forceinline__ void grid_barrier_n(int* bar, int n) {
    __syncthreads();
    if (threadIdx.x == 0) {
        __threadfence();   // release: writeback this block's phase writes
        __hip_atomic_fetch_add(bar, 1, __ATOMIC_RELAXED, __HIP_MEMORY_SCOPE_AGENT);
        while (__hip_atomic_load(bar, __ATOMIC_RELAXED, __HIP_MEMORY_SCOPE_AGENT) < n)
            __builtin_amdgcn_s_sleep(8);
        __threadfence();   // acquire: invalidate stale L1/L2 once
    }
    __syncthreads();
}

__launch_bounds__(FT, 2)
__global__ void forest_kernel(const int* __restrict__ input,
                              const int* __restrict__ node_ids,
                              const int* __restrict__ left,
                              const int* __restrict__ right,
                              const int* __restrict__ last,
                              const float* __restrict__ emb,
                              const float* __restrict__ Wl, const float* __restrict__ Wlb,
                              const float* __restrict__ Wr, const float* __restrict__ Wrb,
                              int* counts, int* rootSlot, int4* lists,
                              float* leafC, __half* leafHh,
                              __half* WT, float* biasSum,
                              float* hInt, float* cInt, __half* hH,
                              unsigned char* used, float4* out) {
    __shared__ SharedU S;
    int t = threadIdx.x;
    int* bar = counts + 16;   // counts[16..24]: 9 barrier slots, pre-zeroed

    // ================= P0: leaf states, WT transpose, biasSum, mark =================
    for (int r = blockIdx.x * 4 + (t >> 7); r < SCV; r += gridDim.x * 4) {
        int i = t & 127;
        const float* e = emb + r * 640;
        float c = sigm(e[i]) * tanhf(e[512 + i]);
        float h = sigm(e[384 + i]) * tanhf(c);
        leafC[r * 128 + i] = c;
        leafHh[r * 128 + i] = __float2half(h);
    }
    // mark used tokens
    for (int i = blockIdx.x * FT + t; i < 16384; i += gridDim.x * FT)
        used[input[i]] = 1;
    // bias sum
    if (blockIdx.x == 40)
        for (int i = t; i < 640; i += FT) biasSum[i] = Wlb[i] + Wrb[i];
    // WT[n][k] = fp16([Wl;Wr][k][n]); 40 tiles of 64x64
    for (int tile = blockIdx.x; tile < 40; tile += gridDim.x) {
        int kb = (tile & 3) * 64, nb = (tile >> 2) * 64;
        int tx = t & 63, ty = (t >> 6) & 3;
        if (t < 256) {
            for (int kk = ty; kk < 64; kk += 4) {
                int k = kb + kk;
                const float* Wsrc = (k < 128) ? (Wl + k * 640) : (Wr + (k - 128) * 640);
                S.w.T[kk][tx] = Wsrc[nb + tx];
            }
        }
        __syncthreads();
        if (t < 256) {
            for (int nn = ty; nn < 64; nn += 4)
                WT[(nb + nn) * 256 + kb + tx] = __float2half(S.w.T[tx][nn]);
        }
        __syncthreads();
    }
    grid_barrier_n(&bar[0], FBLK);

    // ================= P1: metadata (heights, compact slots, per-height lists) ======
    {
        int tile = blockIdx.x;                 // tiles 0..156 active
        bool act = (tile * MT) < V;
        if (t < 8) S.m.locCnt[t] = 0;
        __syncthreads();
        int v = tile * MT + t;
        int nInt = 0;
        if (act && t < MT && v < V && used[v]) {
            int l15[LL], r15[LL], id15[LL];
#pragma unroll
            for (int j = 0; j < LL; ++j) {
                l15[j]  = left[v * LL + j];
                r15[j]  = right[v * LL + j];
                id15[j] = node_ids[v * LL + j];
            }
            int lastv = last[v];
#pragma unroll
            for (int j = 0; j < LL; ++j) {
                if (j <= lastv) {
                    int l = l15[j];
                    if (l < 0) {
                        S.m.sHei[t][j] = 0;
                        S.m.sRef[t][j] = LEAF_BIT | id15[j];
                    } else {
                        int r = r15[j];
                        int hl = S.m.sHei[t][l], hr = S.m.sHei[t][r];
                        int hh = 1 + (hl > hr ? hl : hr);
                        S.m.sHei[t][j] = hh;
                        int pos = atomicAdd(&S.m.locCnt[hh], 1);
                        int flag = (j == lastv) ? ROOT_BIT : 0;
                        S.m.ebuf[t][nInt] = make_int4(nInt | flag, id15[j],
                                                      S.m.sRef[t][l], S.m.sRef[t][r]);
                        S.m.ebin[t][nInt] = (hh << 16) | pos;
                        S.m.sRef[t][j] = nInt;
                        ++nInt;
                    }
                }
            }
        }
        if (t < MT) S.m.scanBuf[t] = nInt;
        __syncthreads();
        for (int d = 1; d < MT; d <<= 1) {
            int val = (t >= d && t < MT) ? S.m.scanBuf[t - d] : 0;
            __syncthreads();
            if (t < MT) S.m.scanBuf[t] += val;
            __syncthreads();
        }
        if (act && t == 0) S.m.blockBase = atomicAdd(&counts[31], S.m.scanBuf[MT - 1]);
        if (act && t < 8) {
            int c = S.m.locCnt[t];
            S.m.basePos[t] = c ? atomicAdd(&counts[t], c) : 0;
        }
        __syncthreads();
        if (act && t < MT) {
            int treeBase = S.m.blockBase + S.m.scanBuf[t] - nInt;
            if (nInt > 0 && v < V) rootSlot[v] = treeBase + nInt - 1;
            for (int e = 0; e < nInt; ++e) {
                int4 E  = S.m.ebuf[t][e];
                int md  = S.m.ebin[t][e];
                int hh  = md >> 16, pos = md & 0xFFFF;
                E.x += treeBase;                                   // ROOT_BIT preserved
                E.z = (E.z & LEAF_BIT) ? E.z : (E.z + treeBase);
                E.w = (E.w & LEAF_BIT) ? E.w : (E.w + treeBase);
                lists[d_listOff[hh] + S.m.basePos[hh] + pos] = E;
            }
        }
    }
    grid_barrier_n(&bar[1], FBLK);

    // ================= P2..P8: MFMA rounds, heights 1..7, unified K=256 =============
    // block = 8 waves; 64 nodes/group; wave w owns cols {128p + 16w + ln15, p=0..4}
    // = the 5 gates of dim 16w+ln15 -> full in-register LSTM epilogue.
    // Heights 5-7 have ~20 groups total: only NTAIL blocks participate (and only
    // they sync at bar[6]/bar[7]); the rest park at the counting pre-gather barrier.
    int lane = t & 63, wave = t >> 6;
    int ln15 = lane & 15, quad = lane >> 4;
    for (int h = 1; h <= 7; ++h) {
        int nBlk = (h <= 4) ? FBLK : NTAIL;
        if ((int)blockIdx.x < nBlk) {
            int cnt = counts[h];
            const int4* list = lists + d_listOff[h];
            int nGroups = (cnt + 63) >> 6;
            for (int grp = blockIdx.x; grp < nGroups; grp += nBlk) {
                int base = grp * 64;
                int rows = cnt - base; if (rows > 64) rows = 64;
                if (t < 64) {
                    int4 E;
                    if (t < rows) E = list[base + t];
                    else { E.x = DUMMY_SLOT; E.y = 0; E.z = LEAF_BIT; E.w = LEAF_BIT; }
                    S.f.meta[t] = E;
                }
                __syncthreads();
                // stage A rows: [hl fp16 (k 0..127) | hr fp16 (k 128..255)]
#pragma unroll
                for (int it = 0; it < 4; ++it) {
                    int idx = t + it * FT;
                    int m = idx >> 5, q = idx & 31;
                    int ref = (q < 16) ? S.f.meta[m].z : S.f.meta[m].w;
                    const __half* hs = (ref & LEAF_BIT) ? leafHh : hH;
                    uint4 vv = *(const uint4*)(hs + (ref & REF_MASK) * 128 + (q & 15) * 8);
                    *(uint4*)(&S.f.Ah[m][q * 8]) = vv;
                }
                // C init: emb + (Wlb+Wrb)
                float bs[5];
#pragma unroll
                for (int p = 0; p < 5; ++p) bs[p] = biasSum[p * 128 + 16 * wave + ln15];
                f32x4 acc[4][5];
#pragma unroll
                for (int c = 0; c < 4; ++c)
#pragma unroll
                    for (int r = 0; r < 4; ++r) {
                        const float* eb = emb + S.f.meta[c * 16 + quad * 4 + r].y * 640
                                              + 16 * wave + ln15;
#pragma unroll
                        for (int p = 0; p < 5; ++p)
                            acc[c][p][r] = eb[p * 128] + bs[p];
                    }
                __syncthreads();
                // K loop: 8 steps of 32; 5 B-frags + 4 A-frags -> 20 independent MFMAs
                const __half* wbase = WT + (16 * wave + ln15) * 256 + quad * 8;
#pragma unroll 2
                for (int kb = 0; kb < 8; ++kb) {
                    f16x8 bf[5];
#pragma unroll
                    for (int p = 0; p < 5; ++p)
                        bf[p] = *(const f16x8*)((const void*)(wbase + p * 32768 + kb * 32));
                    f16x8 af[4];
#pragma unroll
                    for (int c = 0; c < 4; ++c)
                        af[c] = *(const f16x8*)((const void*)&S.f.Ah[c * 16 + ln15][kb * 32 + quad * 8]);
#pragma unroll
                    for (int p = 0; p < 5; ++p)
#pragma unroll
                        for (int c = 0; c < 4; ++c)
                            acc[c][p] = __builtin_amdgcn_mfma_f32_16x16x32_f16(af[c], bf[p], acc[c][p], 0, 0, 0);
                }
                // in-register LSTM epilogue: dim d = 16*wave + ln15, gates = p
                int d = 16 * wave + ln15;
#pragma unroll
                for (int c = 0; c < 4; ++c)
#pragma unroll
                    for (int r = 0; r < 4; ++r) {
                        int4 E = S.f.meta[c * 16 + quad * 4 + r];
                        float ig = acc[c][0][r], lfg = acc[c][1][r], rfg = acc[c][2][r];
                        float og = acc[c][3][r], ug = acc[c][4][r];
                        float cl = ((E.z & LEAF_BIT) ? leafC : cInt)[(E.z & REF_MASK) * 128 + d];
                        float cr = ((E.w & LEAF_BIT) ? leafC : cInt)[(E.w & REF_MASK) * 128 + d];
                        float cc = sigm(ig) * tanhf(ug) + sigm(lfg) * cl + sigm(rfg) * cr;
                        float hh2 = sigm(og) * tanhf(cc);
                        int slot = E.x & SLOT_MASK;
                        if (E.x & ROOT_BIT) {
                            hInt[slot * 128 + d] = hh2;      // root: only f32 h read (gather)
                        } else {
                            cInt[slot * 128 + d] = cc;       // non-root: c + fp16 h read
                            hH[slot * 128 + d] = __float2half(hh2);
                        }
                    }
                __syncthreads();   // protect meta/Ah before next group
            }
        }
        if (h <= 4)      grid_barrier_n(&bar[1 + h], FBLK);                    // bar[2..5]
        else if (h < 7) { if ((int)blockIdx.x < NTAIL) grid_barrier_n(&bar[1 + h], NTAIL); } // bar[6],[7]
    }
    grid_barrier_n(&bar[8], FBLK);   // pre-gather: everyone (tail blocks arrive last)

    // ================= P9: gather out[b,s,:] = h_root[input[b,s]] ===================
    for (int idx = blockIdx.x * FT + t; idx < OUTN / 4; idx += gridDim.x * FT) {
        int token = input[idx >> 5];
        int d = idx & 31;
        out[idx] = ((const float4*)hInt)[rootSlot[token] * 32 + d];
    }
}

extern "C" void kernel_launch(void* const* d_in, const int* in_sizes, int n_in,
                              void* d_out, int out_size, void* d_ws, size_t ws_size,
                              hipStream_t stream) {
    const int*   input    = (const int*)d_in[0];
    const int*   node_ids = (const int*)d_in[1];
    const int*   left     = (const int*)d_in[2];
    const int*   right    = (const int*)d_in[3];
    const int*   last     = (const int*)d_in[4];
    const float* emb      = (const float*)d_in[5];
    const float* Wl       = (const float*)d_in[6];
    const float* Wlb      = (const float*)d_in[7];
    const float* Wr       = (const float*)d_in[8];
    const float* Wrb      = (const float*)d_in[9];
    float* out = (float*)d_out;

    char* ws = (char*)d_ws;
    int*    counts   = (int*)(ws + OFF_COUNTS);
    int*    rootSlot = (int*)(ws + OFF_ROOT);
    int4*   lists    = (int4*)(ws + OFF_LISTS);
    float*  leafC    = (float*)(ws + OFF_LEAFC);
    __half* leafHh   = (__half*)(ws + OFF_LEAFHH);
    __half* WT       = (__half*)(ws + OFF_WT);
    float*  biasSum  = (float*)(ws + OFF_BIAS);
    float*  hInt     = (float*)(ws + OFF_HINT);
    float*  cInt     = (float*)(ws + OFF_CINT);
    __half* hH       = (__half*)(ws + OFF_HH);
    unsigned char* usedp = (unsigned char*)(ws + OFF_USED);

    (void)hipMemsetAsync(counts, 0, 128, stream);   // counts + barrier slots
    (void)hipMemsetAsync(usedp, 0, V, stream);

    forest_kernel<<<FBLK, FT, 0, stream>>>(input, node_ids, left, right, last,
                                           emb, Wl, Wlb, Wr, Wrb,
                                           counts, rootSlot, lists, leafC, leafHh,
                                           WT, biasSum, hInt, cInt, hH,
                                           usedp, (float4*)out);
}

// Round 4
// 334.117 us; speedup vs baseline: 3.0796x; 1.3577x over previous
//
#include <hip/hip_runtime.h>
#include <hip/hip_fp16.h>
#include <math.h>

// Problem constants
#define V    20000
#define SCV  4000
#define LL   15
#define OUTN (16384 * 128)   // B*S*D

#define LEAF_BIT 0x40000000
#define REF_MASK 0x3FFFFFFF
#define ROOT_BIT 0x20000000   // on E.x only: node is a tree root (write hInt only)
#define SLOT_MASK 0x1FFFFFFF
#define DUMMY_SLOT 89999     // total internal nodes ~80k < 89999

// ---- workspace layout (bytes) ----
#define OFF_COUNTS 0
#define OFF_ROOT   128
#define OFF_LISTS  80384
#define OFF_LEAFC  5968384
#define OFF_LEAFHH 8016384
#define OFF_WT     19280384
#define OFF_BIAS   19608064
#define OFF_HINT   19610624
#define OFF_CINT   65690624
#define OFF_HH     111770624
#define OFF_USED   134810624

// per-height lists: h1@0 (cap 80000), h2@80000, h3@120000, h4@160000,
// h5@180000, h6@200000, h7@220000
__device__ __constant__ int d_listOff[8] = {0, 0, 80000, 120000, 160000, 180000, 200000, 220000};

#define MT 128

typedef _Float16 f16x8 __attribute__((ext_vector_type(8)));
typedef float    f32x4 __attribute__((ext_vector_type(4)));

__device__ __forceinline__ float sigm(float x) { return 1.0f / (1.0f + expf(-x)); }

// ---------------- prep: leaf states + WT transpose + biasSum + mark ----------------
// grid 1024 x 256. Blocks 0..39 also do one 64x64 WT tile; block 41 does biasSum.
__global__ void prep_kernel(const int* __restrict__ input,
                            const float* __restrict__ emb,
                            const float* __restrict__ Wl, const float* __restrict__ Wlb,
                            const float* __restrict__ Wr, const float* __restrict__ Wrb,
                            float* __restrict__ leafC, __half* __restrict__ leafHh,
                            __half* __restrict__ WT, float* __restrict__ biasSum,
                            unsigned char* __restrict__ used) {
    __shared__ float T[64][65];
    int t = threadIdx.x, bid = blockIdx.x;
    // leaf (h,c) per sub-char id: 2 rows per block-iter
    for (int r = bid * 2 + (t >> 7); r < SCV; r += gridDim.x * 2) {
        int i = t & 127;
        const float* e = emb + r * 640;
        float c = sigm(e[i]) * tanhf(e[512 + i]);
        float h = sigm(e[384 + i]) * tanhf(c);
        leafC[r * 128 + i] = c;
        leafHh[r * 128 + i] = __float2half(h);
    }
    // mark used tokens
    for (int i = bid * 256 + t; i < 16384; i += gridDim.x * 256)
        used[input[i]] = 1;
    // bias sum
    if (bid == 41)
        for (int i = t; i < 640; i += 256) biasSum[i] = Wlb[i] + Wrb[i];
    // WT[n][k] = fp16([Wl;Wr][k][n]); 40 tiles of 64x64, one per block 0..39
    if (bid < 40) {
        int kb = (bid & 3) * 64, nb = (bid >> 2) * 64;
        int tx = t & 63, ty = t >> 6;            // 256 threads: ty 0..3
        for (int kk = ty; kk < 64; kk += 4) {
            int k = kb + kk;
            const float* Wsrc = (k < 128) ? (Wl + k * 640) : (Wr + (k - 128) * 640);
            T[kk][tx] = Wsrc[nb + tx];
        }
        __syncthreads();
        for (int nn = ty; nn < 64; nn += 4)
            WT[(nb + nn) * 256 + kb + tx] = __float2half(T[tx][nn]);
    }
}

// ---------------- metadata: heights, compact slots, per-height lists ----------------
__global__ void meta_kernel(const int* __restrict__ node_ids,
                            const int* __restrict__ left,
                            const int* __restrict__ right,
                            const int* __restrict__ last,
                            const unsigned char* __restrict__ used,
                            int* __restrict__ counts,
                            int* __restrict__ rootSlot,
                            int4* __restrict__ lists) {
    __shared__ int  sHei[MT][17];
    __shared__ int  sRef[MT][17];
    __shared__ int4 ebuf[MT][7];
    __shared__ int  ebin[MT][7];
    __shared__ int  locCnt[8];
    __shared__ int  basePos[8];
    __shared__ int  scanBuf[MT];
    __shared__ int  blockBase;

    int tid = threadIdx.x;
    if (tid < 8) locCnt[tid] = 0;
    __syncthreads();

    int v = blockIdx.x * MT + tid;
    int nInt = 0;
    if (v < V && used[v]) {
        int l15[LL], r15[LL], id15[LL];
#pragma unroll
        for (int j = 0; j < LL; ++j) {
            l15[j]  = left[v * LL + j];
            r15[j]  = right[v * LL + j];
            id15[j] = node_ids[v * LL + j];
        }
        int lastv = last[v];
#pragma unroll
        for (int j = 0; j < LL; ++j) {
            if (j <= lastv) {
                int l = l15[j];
                if (l < 0) {
                    sHei[tid][j] = 0;
                    sRef[tid][j] = LEAF_BIT | id15[j];
                } else {
                    int r = r15[j];
                    int hl = sHei[tid][l], hr = sHei[tid][r];
                    int hh = 1 + (hl > hr ? hl : hr);
                    sHei[tid][j] = hh;
                    int pos = atomicAdd(&locCnt[hh], 1);
                    int flag = (j == lastv) ? ROOT_BIT : 0;
                    ebuf[tid][nInt] = make_int4(nInt | flag, id15[j], sRef[tid][l], sRef[tid][r]);
                    ebin[tid][nInt] = (hh << 16) | pos;
                    sRef[tid][j] = nInt;
                    ++nInt;
                }
            }
        }
    }
    // block-level inclusive scan of nInt -> compact slot bases
    scanBuf[tid] = nInt;
    __syncthreads();
    for (int d = 1; d < MT; d <<= 1) {
        int val = (tid >= d) ? scanBuf[tid - d] : 0;
        __syncthreads();
        scanBuf[tid] += val;
        __syncthreads();
    }
    if (tid == 0) blockBase = atomicAdd(&counts[31], scanBuf[MT - 1]);
    if (tid < 8) {
        int c = locCnt[tid];
        basePos[tid] = c ? atomicAdd(&counts[tid], c) : 0;
    }
    __syncthreads();
    int treeBase = blockBase + scanBuf[tid] - nInt;
    if (v < V && nInt > 0) rootSlot[v] = treeBase + nInt - 1;
    for (int e = 0; e < nInt; ++e) {
        int4 E  = ebuf[tid][e];
        int md  = ebin[tid][e];
        int hh  = md >> 16, pos = md & 0xFFFF;
        E.x += treeBase;                                   // ROOT_BIT preserved
        E.z = (E.z & LEAF_BIT) ? E.z : (E.z + treeBase);
        E.w = (E.w & LEAF_BIT) ? E.w : (E.w + treeBase);
        lists[d_listOff[hh] + basePos[hh] + pos] = E;
    }
}

// ---------------- MFMA round: all heights 1..7, unified K=256 ----------------
// block = 8 waves; 64 nodes/group; wave w owns cols {128p + 16w + ln15, p=0..4}
// = the 5 gates of dim 16w+ln15 -> full in-register LSTM epilogue.
// Each B fragment (WT, L2-hot 320KB) feeds 4 MFMAs (one per 16-node chunk).
__launch_bounds__(512, 2)
__global__ void round_mfma(const int4* __restrict__ list, const int* __restrict__ cntPtr,
                           const float* __restrict__ emb, const __half* __restrict__ WT,
                           const float* __restrict__ biasSum,
                           const __half* __restrict__ leafHh, const float* __restrict__ leafC,
                           float* __restrict__ hInt, float* __restrict__ cInt,
                           __half* __restrict__ hH) {
    __shared__ __half Ah[64][264];   // +8 fp16 pad per row
    __shared__ int4 meta[64];
    int cnt = *cntPtr;
    int nGroups = (cnt + 63) >> 6;
    int t = threadIdx.x;
    int lane = t & 63, wave = t >> 6;        // 8 waves
    int ln15 = lane & 15, quad = lane >> 4;
    for (int grp = blockIdx.x; grp < nGroups; grp += gridDim.x) {
        int base = grp * 64;
        int rows = cnt - base; if (rows > 64) rows = 64;
        if (t < 64) {
            int4 E;
            if (t < rows) E = list[base + t];
            else { E.x = DUMMY_SLOT; E.y = 0; E.z = LEAF_BIT; E.w = LEAF_BIT; }
            meta[t] = E;
        }
        __syncthreads();
        // stage A rows: [hl fp16 (k 0..127) | hr fp16 (k 128..255)]
#pragma unroll
        for (int it = 0; it < 4; ++it) {
            int idx = t + it * 512;
            int m = idx >> 5, q = idx & 31;
            int ref = (q < 16) ? meta[m].z : meta[m].w;
            const __half* hs = (ref & LEAF_BIT) ? leafHh : hH;
            uint4 v = *(const uint4*)(hs + (ref & REF_MASK) * 128 + (q & 15) * 8);
            *(uint4*)(&Ah[m][q * 8]) = v;
        }
        // C init: emb + (Wlb+Wrb); gate p lives at col offset 128p
        float bs[5];
#pragma unroll
        for (int p = 0; p < 5; ++p) bs[p] = biasSum[p * 128 + 16 * wave + ln15];
        f32x4 acc[4][5];
#pragma unroll
        for (int c = 0; c < 4; ++c)
#pragma unroll
            for (int r = 0; r < 4; ++r) {
                const float* eb = emb + meta[c * 16 + quad * 4 + r].y * 640 + 16 * wave + ln15;
#pragma unroll
                for (int p = 0; p < 5; ++p)
                    acc[c][p][r] = eb[p * 128] + bs[p];
            }
        __syncthreads();
        // K loop: 8 steps of 32; 5 B-frags + 4 A-frags -> 20 independent MFMAs
        const __half* wbase = WT + (16 * wave + ln15) * 256 + quad * 8;
#pragma unroll 2
        for (int kb = 0; kb < 8; ++kb) {
            f16x8 bf[5];
#pragma unroll
            for (int p = 0; p < 5; ++p)
                bf[p] = *(const f16x8*)((const void*)(wbase + p * 32768 + kb * 32));
            f16x8 af[4];
#pragma unroll
            for (int c = 0; c < 4; ++c)
                af[c] = *(const f16x8*)((const void*)&Ah[c * 16 + ln15][kb * 32 + quad * 8]);
#pragma unroll
            for (int p = 0; p < 5; ++p)
#pragma unroll
                for (int c = 0; c < 4; ++c)
                    acc[c][p] = __builtin_amdgcn_mfma_f32_16x16x32_f16(af[c], bf[p], acc[c][p], 0, 0, 0);
        }
        // in-register LSTM epilogue: dim d = 16*wave + ln15, gates = p
        int d = 16 * wave + ln15;
#pragma unroll
        for (int c = 0; c < 4; ++c)
#pragma unroll
            for (int r = 0; r < 4; ++r) {
                int4 E = meta[c * 16 + quad * 4 + r];
                float ig = acc[c][0][r], lfg = acc[c][1][r], rfg = acc[c][2][r];
                float og = acc[c][3][r], ug = acc[c][4][r];
                float cl = ((E.z & LEAF_BIT) ? leafC : cInt)[(E.z & REF_MASK) * 128 + d];
                float cr = ((E.w & LEAF_BIT) ? leafC : cInt)[(E.w & REF_MASK) * 128 + d];
                float cc = sigm(ig) * tanhf(ug) + sigm(lfg) * cl + sigm(rfg) * cr;
                float hh2 = sigm(og) * tanhf(cc);
                int slot = E.x & SLOT_MASK;
                if (E.x & ROOT_BIT) {
                    hInt[slot * 128 + d] = hh2;      // root: only f32 h is read (gather)
                } else {
                    cInt[slot * 128 + d] = cc;       // non-root: c + fp16 h are read
                    hH[slot * 128 + d] = __float2half(hh2);
                }
            }
        __syncthreads();   // protect meta/Ah before next group
    }
}

// ---------------- final gather: out[b,s,:] = h_root[input[b,s]] ----------------
__global__ void gather_kernel(const int* __restrict__ input,
                              const int* __restrict__ rootSlot,
                              const float* __restrict__ hInt,
                              float4* __restrict__ out) {
    int idx = blockIdx.x * 256 + threadIdx.x;   // < OUTN/4
    int token = input[idx >> 5];
    int d = idx & 31;
    out[idx] = ((const float4*)hInt)[rootSlot[token] * 32 + d];
}

extern "C" void kernel_launch(void* const* d_in, const int* in_sizes, int n_in,
                              void* d_out, int out_size, void* d_ws, size_t ws_size,
                              hipStream_t stream) {
    const int*   input    = (const int*)d_in[0];
    const int*   node_ids = (const int*)d_in[1];
    const int*   left     = (const int*)d_in[2];
    const int*   right    = (const int*)d_in[3];
    const int*   last     = (const int*)d_in[4];
    const float* emb      = (const float*)d_in[5];
    const float* Wl       = (const float*)d_in[6];
    const float* Wlb      = (const float*)d_in[7];
    const float* Wr       = (const float*)d_in[8];
    const float* Wrb      = (const float*)d_in[9];
    float* out = (float*)d_out;

    char* ws = (char*)d_ws;
    int*    counts   = (int*)(ws + OFF_COUNTS);
    int*    rootSlot = (int*)(ws + OFF_ROOT);
    int4*   lists    = (int4*)(ws + OFF_LISTS);
    float*  leafC    = (float*)(ws + OFF_LEAFC);
    __half* leafHh   = (__half*)(ws + OFF_LEAFHH);
    __half* WT       = (__half*)(ws + OFF_WT);
    float*  biasSum  = (float*)(ws + OFF_BIAS);
    float*  hInt     = (float*)(ws + OFF_HINT);
    float*  cInt     = (float*)(ws + OFF_CINT);
    __half* hH       = (__half*)(ws + OFF_HH);
    unsigned char* usedp = (unsigned char*)(ws + OFF_USED);

    (void)hipMemsetAsync(counts, 0, 128, stream);
    (void)hipMemsetAsync(usedp, 0, V, stream);

    prep_kernel<<<1024, 256, 0, stream>>>(input, emb, Wl, Wlb, Wr, Wrb,
                                          leafC, leafHh, WT, biasSum, usedp);
    meta_kernel<<<(V + MT - 1) / MT, MT, 0, stream>>>(node_ids, left, right, last, usedp,
                                                      counts, rootSlot, lists);

    static const int h_listOff[8] = {0, 0, 80000, 120000, 160000, 180000, 200000, 220000};
    static const int h_grid[8]    = {0, 512, 512, 256, 128, 32, 8, 4};
    for (int h = 1; h <= 7; ++h) {
        round_mfma<<<h_grid[h], 512, 0, stream>>>(
            lists + h_listOff[h], counts + h,
            emb, WT, biasSum, leafHh, leafC, hInt, cInt, hH);
    }

    gather_kernel<<<OUTN / 4 / 256, 256, 0, stream>>>(input, rootSlot, hInt, (float4*)out);
}

// Round 5
// 326.189 us; speedup vs baseline: 3.1545x; 1.0243x over previous
//
#include <hip/hip_runtime.h>
#include <hip/hip_fp16.h>
#include <math.h>

// Problem constants
#define V    20000
#define SCV  4000
#define LL   15
#define OUTN (16384 * 128)   // B*S*D

#define LEAF_BIT 0x40000000
#define REF_MASK 0x3FFFFFFF
#define ROOT_BIT 0x20000000   // on E.x only: node is a tree root (write hInt only)
#define SLOT_MASK 0x1FFFFFFF
#define DUMMY_SLOT 89999     // total internal nodes ~80k < 89999

// ---- workspace layout (bytes) ----
#define OFF_COUNTS 0
#define OFF_ROOT   128
#define OFF_LISTS  80384
#define OFF_LEAFC  5968384
#define OFF_LEAFHH 8016384
#define OFF_WT     19280384
#define OFF_BIAS   19608064
#define OFF_HINT   19610624
#define OFF_CINT   65690624
#define OFF_HH     111770624
#define OFF_USED   134810624

// per-height lists: h1@0 (cap 80000), h2@80000, h3@120000, h4@160000,
// h5@180000, h6@200000, h7@220000
__device__ __constant__ int d_listOff[8] = {0, 0, 80000, 120000, 160000, 180000, 200000, 220000};

#define MT 128

typedef _Float16 f16x8 __attribute__((ext_vector_type(8)));
typedef float    f32x4 __attribute__((ext_vector_type(4)));

__device__ __forceinline__ float sigm(float x) { return 1.0f / (1.0f + expf(-x)); }

// ---------------- prep: leaf states + WT transpose + biasSum + mark ----------------
// grid 1024 x 256. Blocks 0..39 also do one 64x64 WT tile; block 41 does biasSum.
__global__ void prep_kernel(const int* __restrict__ input,
                            const float* __restrict__ emb,
                            const float* __restrict__ Wl, const float* __restrict__ Wlb,
                            const float* __restrict__ Wr, const float* __restrict__ Wrb,
                            float* __restrict__ leafC, __half* __restrict__ leafHh,
                            __half* __restrict__ WT, float* __restrict__ biasSum,
                            unsigned char* __restrict__ used) {
    __shared__ float T[64][65];
    int t = threadIdx.x, bid = blockIdx.x;
    // leaf (h,c) per sub-char id: 2 rows per block-iter
    for (int r = bid * 2 + (t >> 7); r < SCV; r += gridDim.x * 2) {
        int i = t & 127;
        const float* e = emb + r * 640;
        float c = sigm(e[i]) * tanhf(e[512 + i]);
        float h = sigm(e[384 + i]) * tanhf(c);
        leafC[r * 128 + i] = c;
        leafHh[r * 128 + i] = __float2half(h);
    }
    // mark used tokens
    for (int i = bid * 256 + t; i < 16384; i += gridDim.x * 256)
        used[input[i]] = 1;
    // bias sum
    if (bid == 41)
        for (int i = t; i < 640; i += 256) biasSum[i] = Wlb[i] + Wrb[i];
    // WT[n][k] = fp16([Wl;Wr][k][n]); 40 tiles of 64x64, one per block 0..39
    if (bid < 40) {
        int kb = (bid & 3) * 64, nb = (bid >> 2) * 64;
        int tx = t & 63, ty = t >> 6;            // 256 threads: ty 0..3
        for (int kk = ty; kk < 64; kk += 4) {
            int k = kb + kk;
            const float* Wsrc = (k < 128) ? (Wl + k * 640) : (Wr + (k - 128) * 640);
            T[kk][tx] = Wsrc[nb + tx];
        }
        __syncthreads();
        for (int nn = ty; nn < 64; nn += 4)
            WT[(nb + nn) * 256 + kb + tx] = __float2half(T[tx][nn]);
    }
}

// ---------------- metadata: heights, compact slots, per-height lists ----------------
__global__ void meta_kernel(const int* __restrict__ node_ids,
                            const int* __restrict__ left,
                            const int* __restrict__ right,
                            const int* __restrict__ last,
                            const unsigned char* __restrict__ used,
                            int* __restrict__ counts,
                            int* __restrict__ rootSlot,
                            int4* __restrict__ lists) {
    __shared__ int  sHei[MT][17];
    __shared__ int  sRef[MT][17];
    __shared__ int4 ebuf[MT][7];
    __shared__ int  ebin[MT][7];
    __shared__ int  locCnt[8];
    __shared__ int  basePos[8];
    __shared__ int  scanBuf[MT];
    __shared__ int  blockBase;

    int tid = threadIdx.x;
    if (tid < 8) locCnt[tid] = 0;
    __syncthreads();

    int v = blockIdx.x * MT + tid;
    int nInt = 0;
    if (v < V && used[v]) {
        int l15[LL], r15[LL], id15[LL];
#pragma unroll
        for (int j = 0; j < LL; ++j) {
            l15[j]  = left[v * LL + j];
            r15[j]  = right[v * LL + j];
            id15[j] = node_ids[v * LL + j];
        }
        int lastv = last[v];
#pragma unroll
        for (int j = 0; j < LL; ++j) {
            if (j <= lastv) {
                int l = l15[j];
                if (l < 0) {
                    sHei[tid][j] = 0;
                    sRef[tid][j] = LEAF_BIT | id15[j];
                } else {
                    int r = r15[j];
                    int hl = sHei[tid][l], hr = sHei[tid][r];
                    int hh = 1 + (hl > hr ? hl : hr);
                    sHei[tid][j] = hh;
                    int pos = atomicAdd(&locCnt[hh], 1);
                    int flag = (j == lastv) ? ROOT_BIT : 0;
                    ebuf[tid][nInt] = make_int4(nInt | flag, id15[j], sRef[tid][l], sRef[tid][r]);
                    ebin[tid][nInt] = (hh << 16) | pos;
                    sRef[tid][j] = nInt;
                    ++nInt;
                }
            }
        }
    }
    // block-level inclusive scan of nInt -> compact slot bases
    scanBuf[tid] = nInt;
    __syncthreads();
    for (int d = 1; d < MT; d <<= 1) {
        int val = (tid >= d) ? scanBuf[tid - d] : 0;
        __syncthreads();
        scanBuf[tid] += val;
        __syncthreads();
    }
    if (tid == 0) blockBase = atomicAdd(&counts[31], scanBuf[MT - 1]);
    if (tid < 8) {
        int c = locCnt[tid];
        basePos[tid] = c ? atomicAdd(&counts[tid], c) : 0;
    }
    __syncthreads();
    int treeBase = blockBase + scanBuf[tid] - nInt;
    if (v < V && nInt > 0) rootSlot[v] = treeBase + nInt - 1;
    for (int e = 0; e < nInt; ++e) {
        int4 E  = ebuf[tid][e];
        int md  = ebin[tid][e];
        int hh  = md >> 16, pos = md & 0xFFFF;
        E.x += treeBase;                                   // ROOT_BIT preserved
        E.z = (E.z & LEAF_BIT) ? E.z : (E.z + treeBase);
        E.w = (E.w & LEAF_BIT) ? E.w : (E.w + treeBase);
        lists[d_listOff[hh] + basePos[hh] + pos] = E;
    }
}

// ---------------- MFMA round: all heights 1..7, unified K=256 ----------------
// block = 8 waves, 32 nodes/group (2 chunks of 16).
// wave w owns cols {128p + 16w + ln15, p=0..4} = the 5 gates of dim 16w+ln15
// -> full in-register LSTM epilogue.
// acc[2][5] = 40 f32/lane (was 80): total regs/wave ~125 -> 4 waves/SIMD
// -> 2 blocks/CU resident and ~40 VGPRs free for load batching (MLP).
__launch_bounds__(512, 4)
__global__ void round_mfma(const int4* __restrict__ list, const int* __restrict__ cntPtr,
                           const float* __restrict__ emb, const __half* __restrict__ WT,
                           const float* __restrict__ biasSum,
                           const __half* __restrict__ leafHh, const float* __restrict__ leafC,
                           float* __restrict__ hInt, float* __restrict__ cInt,
                           __half* __restrict__ hH) {
    __shared__ __half Ah[32][264];   // +8 fp16 pad per row
    __shared__ int4 meta[32];
    int cnt = *cntPtr;
    int nGroups = (cnt + 31) >> 5;
    int t = threadIdx.x;
    int lane = t & 63, wave = t >> 6;        // 8 waves
    int ln15 = lane & 15, quad = lane >> 4;
    for (int grp = blockIdx.x; grp < nGroups; grp += gridDim.x) {
        int base = grp * 32;
        int rows = cnt - base; if (rows > 32) rows = 32;
        if (t < 32) {
            int4 E;
            if (t < rows) E = list[base + t];
            else { E.x = DUMMY_SLOT; E.y = 0; E.z = LEAF_BIT; E.w = LEAF_BIT; }
            meta[t] = E;
        }
        __syncthreads();
        // stage A rows: [hl fp16 (k 0..127) | hr fp16 (k 128..255)], 2 loads/thread
#pragma unroll
        for (int it = 0; it < 2; ++it) {
            int idx = t + it * 512;
            int m = idx >> 5, q = idx & 31;
            int ref = (q < 16) ? meta[m].z : meta[m].w;
            const __half* hs = (ref & LEAF_BIT) ? leafHh : hH;
            uint4 v = *(const uint4*)(hs + (ref & REF_MASK) * 128 + (q & 15) * 8);
            *(uint4*)(&Ah[m][q * 8]) = v;
        }
        // C init: emb + (Wlb+Wrb); gate p lives at col offset 128p
        float bs[5];
#pragma unroll
        for (int p = 0; p < 5; ++p) bs[p] = biasSum[p * 128 + 16 * wave + ln15];
        f32x4 acc[2][5];
#pragma unroll
        for (int c = 0; c < 2; ++c)
#pragma unroll
            for (int r = 0; r < 4; ++r) {
                const float* eb = emb + meta[c * 16 + quad * 4 + r].y * 640 + 16 * wave + ln15;
#pragma unroll
                for (int p = 0; p < 5; ++p)
                    acc[c][p][r] = eb[p * 128] + bs[p];
            }
        __syncthreads();
        // K loop: 8 steps of 32; 5 B-frags + 2 A-frags -> 10 independent MFMAs
        const __half* wbase = WT + (16 * wave + ln15) * 256 + quad * 8;
#pragma unroll 2
        for (int kb = 0; kb < 8; ++kb) {
            f16x8 bf[5];
#pragma unroll
            for (int p = 0; p < 5; ++p)
                bf[p] = *(const f16x8*)((const void*)(wbase + p * 32768 + kb * 32));
            f16x8 af[2];
#pragma unroll
            for (int c = 0; c < 2; ++c)
                af[c] = *(const f16x8*)((const void*)&Ah[c * 16 + ln15][kb * 32 + quad * 8]);
#pragma unroll
            for (int p = 0; p < 5; ++p)
#pragma unroll
                for (int c = 0; c < 2; ++c)
                    acc[c][p] = __builtin_amdgcn_mfma_f32_16x16x32_f16(af[c], bf[p], acc[c][p], 0, 0, 0);
        }
        // in-register LSTM epilogue: dim d = 16*wave + ln15, gates = p
        int d = 16 * wave + ln15;
#pragma unroll
        for (int c = 0; c < 2; ++c)
#pragma unroll
            for (int r = 0; r < 4; ++r) {
                int4 E = meta[c * 16 + quad * 4 + r];
                float ig = acc[c][0][r], lfg = acc[c][1][r], rfg = acc[c][2][r];
                float og = acc[c][3][r], ug = acc[c][4][r];
                float cl = ((E.z & LEAF_BIT) ? leafC : cInt)[(E.z & REF_MASK) * 128 + d];
                float cr = ((E.w & LEAF_BIT) ? leafC : cInt)[(E.w & REF_MASK) * 128 + d];
                float cc = sigm(ig) * tanhf(ug) + sigm(lfg) * cl + sigm(rfg) * cr;
                float hh2 = sigm(og) * tanhf(cc);
                int slot = E.x & SLOT_MASK;
                if (E.x & ROOT_BIT) {
                    hInt[slot * 128 + d] = hh2;      // root: only f32 h is read (gather)
                } else {
                    cInt[slot * 128 + d] = cc;       // non-root: c + fp16 h are read
                    hH[slot * 128 + d] = __float2half(hh2);
                }
            }
        __syncthreads();   // protect meta/Ah before next group
    }
}

// ---------------- final gather: out[b,s,:] = h_root[input[b,s]] ----------------
__global__ void gather_kernel(const int* __restrict__ input,
                              const int* __restrict__ rootSlot,
                              const float* __restrict__ hInt,
                              float4* __restrict__ out) {
    int idx = blockIdx.x * 256 + threadIdx.x;   // < OUTN/4
    int token = input[idx >> 5];
    int d = idx & 31;
    out[idx] = ((const float4*)hInt)[rootSlot[token] * 32 + d];
}

extern "C" void kernel_launch(void* const* d_in, const int* in_sizes, int n_in,
                              void* d_out, int out_size, void* d_ws, size_t ws_size,
                              hipStream_t stream) {
    const int*   input    = (const int*)d_in[0];
    const int*   node_ids = (const int*)d_in[1];
    const int*   left     = (const int*)d_in[2];
    const int*   right    = (const int*)d_in[3];
    const int*   last     = (const int*)d_in[4];
    const float* emb      = (const float*)d_in[5];
    const float* Wl       = (const float*)d_in[6];
    const float* Wlb      = (const float*)d_in[7];
    const float* Wr       = (const float*)d_in[8];
    const float* Wrb      = (const float*)d_in[9];
    float* out = (float*)d_out;

    char* ws = (char*)d_ws;
    int*    counts   = (int*)(ws + OFF_COUNTS);
    int*    rootSlot = (int*)(ws + OFF_ROOT);
    int4*   lists    = (int4*)(ws + OFF_LISTS);
    float*  leafC    = (float*)(ws + OFF_LEAFC);
    __half* leafHh   = (__half*)(ws + OFF_LEAFHH);
    __half* WT       = (__half*)(ws + OFF_WT);
    float*  biasSum  = (float*)(ws + OFF_BIAS);
    float*  hInt     = (float*)(ws + OFF_HINT);
    float*  cInt     = (float*)(ws + OFF_CINT);
    __half* hH       = (__half*)(ws + OFF_HH);
    unsigned char* usedp = (unsigned char*)(ws + OFF_USED);

    (void)hipMemsetAsync(counts, 0, 128, stream);
    (void)hipMemsetAsync(usedp, 0, V, stream);

    prep_kernel<<<1024, 256, 0, stream>>>(input, emb, Wl, Wlb, Wr, Wrb,
                                          leafC, leafHh, WT, biasSum, usedp);
    meta_kernel<<<(V + MT - 1) / MT, MT, 0, stream>>>(node_ids, left, right, last, usedp,
                                                      counts, rootSlot, lists);

    static const int h_listOff[8] = {0, 0, 80000, 120000, 160000, 180000, 200000, 220000};
    static const int h_grid[8]    = {0, 1024, 512, 256, 128, 32, 16, 8};
    for (int h = 1; h <= 7; ++h) {
        round_mfma<<<h_grid[h], 512, 0, stream>>>(
            lists + h_listOff[h], counts + h,
            emb, WT, biasSum, leafHh, leafC, hInt, cInt, hH);
    }

    gather_kernel<<<OUTN / 4 / 256, 256, 0, stream>>>(input, rootSlot, hInt, (float4*)out);
}